// Round 7
// baseline (245.896 us; speedup 1.0000x reference)
//
#include <hip/hip_runtime.h>
#include <math.h>

#define NTOPK 100
#define QC    6000
#define NC    20
#define EMBED 2700
#define IMGW  1024
#define XSTR  2704          // padded short stride for Xh/Xl rows
#define NKC   8             // gemm K-split chunks (atomic accumulate)
#define NSIMKC 75           // sim K chunks (SKC=36)

typedef __attribute__((ext_vector_type(8))) short short8;
typedef __attribute__((ext_vector_type(4))) float f32x4;

__device__ inline short f32_bf16_rne(float x) {
  const unsigned u = __float_as_uint(x);
  return (short)((u + 0x7fffu + ((u >> 16) & 1u)) >> 16);
}
__device__ inline void split_hl(float x, short& h, short& l) {
  h = f32_bf16_rne(x);
  const float hf = __uint_as_float(((unsigned)(unsigned short)h) << 16);
  l = f32_bf16_rne(x - hf);
}
__device__ inline short8 zero8() {
  short8 z;
#pragma unroll
  for (int i = 0; i < 8; ++i) z[i] = 0;
  return z;
}
// guarded 8-float W load into two float4 regs
__device__ inline void loadW8(const float* __restrict__ W, int n, int k,
                              float4& a, float4& b) {
  a = make_float4(0.f, 0.f, 0.f, 0.f);
  b = make_float4(0.f, 0.f, 0.f, 0.f);
  if (n < EMBED) {
    if (k + 8 <= EMBED) {
      const float4* s = (const float4*)&W[(size_t)n * EMBED + k];
      a = s[0]; b = s[1];
    } else if (k < EMBED) {
      float v[8];
#pragma unroll
      for (int e = 0; e < 8; ++e)
        v[e] = (k + e < EMBED) ? W[(size_t)n * EMBED + k + e] : 0.f;
      a = make_float4(v[0], v[1], v[2], v[3]);
      b = make_float4(v[4], v[5], v[6], v[7]);
    }
  }
}

// ---------------------------------------------------------------------------
// Kernel 1: radix-select top-100 -> xyxy pixel boxes. grid 4, block 256.
// ---------------------------------------------------------------------------
__global__ __launch_bounds__(256) void topk_boxes_kernel(
    const float* __restrict__ g_logits, const float* __restrict__ a_logits,
    const float* __restrict__ g_boxes,  const float* __restrict__ a_boxes,
    float* __restrict__ boxes_px /* [2][2][100][4] */) {
  const int which = blockIdx.x >> 1;
  const int b     = blockIdx.x & 1;
  const float* logits = (which ? a_logits : g_logits) + b * QC;
  const float* boxes  = (which ? a_boxes  : g_boxes)  + b * 300 * 4;
  float* outb = boxes_px + (size_t)(which * 2 + b) * NTOPK * 4;

  __shared__ unsigned keys[QC];
  __shared__ int hist[4096];
  __shared__ int suf[257];
  __shared__ unsigned long long cand[256];
  __shared__ int s_cnt, s_bstar;

  const int tid = threadIdx.x;
  for (int i = tid; i < 4096; i += 256) hist[i] = 0;
  if (tid == 0) s_cnt = 0;
  __syncthreads();
  for (int j = tid; j < QC; j += 256) {
    const unsigned u = __float_as_uint(logits[j]);
    const unsigned k = u ^ ((u >> 31) ? 0xFFFFFFFFu : 0x80000000u);
    keys[j] = k;
    atomicAdd(&hist[k >> 20], 1);
  }
  __syncthreads();
  int cs = 0;
#pragma unroll
  for (int i = 0; i < 16; ++i) cs += hist[tid * 16 + i];
  suf[tid] = cs;
  if (tid == 0) suf[256] = 0;
  __syncthreads();
  for (int d = 1; d < 256; d <<= 1) {
    const int v = (tid + d < 256) ? suf[tid + d] : 0;
    __syncthreads();
    suf[tid] += v;
    __syncthreads();
  }
  if (suf[tid] >= NTOPK && (tid == 255 || suf[tid + 1] < NTOPK)) {
    int acc = suf[tid + 1];
    int bstar = tid * 16;
    for (int bb = tid * 16 + 15; bb >= tid * 16; --bb) {
      if (acc + hist[bb] >= NTOPK) { bstar = bb; break; }
      acc += hist[bb];
    }
    s_bstar = bstar;
  }
  __syncthreads();
  const unsigned bstar = (unsigned)s_bstar;
  for (int j = tid; j < QC; j += 256) {
    if ((keys[j] >> 20) >= bstar) {
      const int pos = atomicAdd(&s_cnt, 1);
      if (pos < 256)
        cand[pos] = (((unsigned long long)(~keys[j])) << 13) | (unsigned)j;
    }
  }
  __syncthreads();
  const int cnt = s_cnt < 256 ? s_cnt : 256;
  if (tid < cnt) {
    const unsigned long long me = cand[tid];
    int rank = 0;
    for (int j = 0; j < cnt; ++j) rank += (cand[j] < me);
    if (rank < NTOPK) {
      const int idx = (int)(me & 8191ULL);
      const int q = idx / NC;
      const float cx = boxes[q*4+0], cy = boxes[q*4+1];
      const float w  = boxes[q*4+2], h  = boxes[q*4+3];
      const float hw = __fmul_rn(0.5f, w), hh = __fmul_rn(0.5f, h);
      outb[rank*4+0] = __fmul_rn(__fsub_rn(cx, hw), 1024.0f);
      outb[rank*4+1] = __fmul_rn(__fsub_rn(cy, hh), 1024.0f);
      outb[rank*4+2] = __fmul_rn(__fadd_rn(cx, hw), 1024.0f);
      outb[rank*4+3] = __fmul_rn(__fadd_rn(cy, hh), 1024.0f);
    }
  }
}

// ---------------------------------------------------------------------------
// Kernel 2: bilinear ROI crops -> bf16 hi/lo X rows (+pos_enc), stride XSTR.
// grid 2400: (which, b*t, c, half). X row u = t*2 + b; pe row = u % 100.
// ---------------------------------------------------------------------------
__global__ __launch_bounds__(256) void roi_kernel(
    const float* __restrict__ g_samples, const float* __restrict__ a_samples,
    const float* __restrict__ boxes_px, const float* __restrict__ pos_enc,
    short* __restrict__ Xgh, short* __restrict__ Xgl,
    short* __restrict__ Xah, short* __restrict__ Xal) {
  const int bi = blockIdx.x;
  const int which = bi / 1200;
  const int rem = bi % 1200;
  const int p = rem / 6;
  const int sub = rem % 6;
  const int c = sub >> 1, half = sub & 1;
  const int b = p / 100, t = p % 100;
  const int u = t * 2 + b;
  const float* ic = (which ? a_samples : g_samples)
                    + ((size_t)b * 3 + c) * IMGW * IMGW;
  const float* bx = boxes_px + ((size_t)(which * 2 + b) * NTOPK + t) * 4;
  short* xh = (which ? Xah : Xgh) + (size_t)u * XSTR + c * 900;
  short* xl = (which ? Xal : Xgl) + (size_t)u * XSTR + c * 900;
  const float* pe = pos_enc + (size_t)(u % 100) * EMBED + c * 900;

  __shared__ float s_wy[30], s_wx[30];
  __shared__ int   s_y0i[30], s_y1i[30], s_x0i[30], s_x1i[30];
  __shared__ float s_valid;

  const float x0 = rintf(bx[0]), y0 = rintf(bx[1]);
  const float x1 = rintf(bx[2]), y1 = rintf(bx[3]);
  const float w = __fsub_rn(x1, x0), h = __fsub_rn(y1, y0);
  const int tid = threadIdx.x;
  if (tid == 0) s_valid = (w > 0.0f && h > 0.0f) ? 1.0f : 0.0f;
  if (tid < 30) {
    const float g  = (float)tid + 0.5f;
    float sy = __fsub_rn(__fdiv_rn(__fmul_rn(g, h), 30.0f), 0.5f);
    const float hm1 = fmaxf(__fsub_rn(h, 1.0f), 0.0f);
    sy = fminf(fmaxf(sy, 0.0f), hm1);
    const float ay = __fadd_rn(y0, sy);
    const float yf = floorf(ay);
    s_wy[tid]  = __fsub_rn(ay, yf);
    s_y0i[tid] = (int)fminf(fmaxf(yf, 0.0f), 1023.0f);
    s_y1i[tid] = (int)fminf(fmaxf(yf + 1.0f, 0.0f), 1023.0f);
  } else if (tid >= 32 && tid < 62) {
    const int i = tid - 32;
    const float g = (float)i + 0.5f;
    float sx = __fsub_rn(__fdiv_rn(__fmul_rn(g, w), 30.0f), 0.5f);
    const float wm1 = fmaxf(__fsub_rn(w, 1.0f), 0.0f);
    sx = fminf(fmaxf(sx, 0.0f), wm1);
    const float ax = __fadd_rn(x0, sx);
    const float xf = floorf(ax);
    s_wx[i]  = __fsub_rn(ax, xf);
    s_x0i[i] = (int)fminf(fmaxf(xf, 0.0f), 1023.0f);
    s_x1i[i] = (int)fminf(fmaxf(xf + 1.0f, 0.0f), 1023.0f);
  }
  __syncthreads();
  const float valid = s_valid;
  const int pbeg = half * 450, pend = pbeg + 450;
  for (int pix = pbeg + tid; pix < pend; pix += 256) {
    const int py = pix / 30, px = pix % 30;
    const int yi0 = s_y0i[py], yi1 = s_y1i[py], xi0 = s_x0i[px], xi1 = s_x1i[px];
    const float wy = s_wy[py], wx = s_wx[px];
    const float p00 = ic[yi0 * IMGW + xi0], p01 = ic[yi0 * IMGW + xi1];
    const float p10 = ic[yi1 * IMGW + xi0], p11 = ic[yi1 * IMGW + xi1];
    const float top = p00 * (1.0f - wx) + p01 * wx;
    const float bot = p10 * (1.0f - wx) + p11 * wx;
    const float val = top * (1.0f - wy) + bot * wy;
    const float x = val * valid + pe[pix];
    short hb, lb;
    split_hl(x, hb, lb);
    xh[pix] = hb;
    xl[pix] = lb;
  }
  if (c == 2 && half == 1 && tid < 4) {
    short* bh = (which ? Xah : Xgh) + (size_t)u * XSTR;
    short* bl = (which ? Xal : Xgl) + (size_t)u * XSTR;
    bh[2700 + tid] = 0;
    bl[2700 + tid] = 0;
  }
}

// ---------------------------------------------------------------------------
// Kernel Z: zero Y (1,080,000 f) + sim (20,000 f), contiguous. 1075 blocks.
// ---------------------------------------------------------------------------
__global__ void zero_kernel(float4* __restrict__ p, int n4) {
  const int i = blockIdx.x * 256 + threadIdx.x;
  if (i < n4) p[i] = make_float4(0.f, 0.f, 0.f, 0.f);
}

// ---------------------------------------------------------------------------
// Kernel 3: Y += X @ W^T (K steps [43kc/8, 43(kc+1)/8)), hi/lo MFMA,
// register-prefetched W stream, atomic accumulate into single Y plane.
// grid (43, 8, 2), 4 waves. A direct global->VGPR; W via 16 KB LDS.
// ---------------------------------------------------------------------------
__global__ __launch_bounds__(256) void gemm_kernel(
    const short* __restrict__ Xgh, const short* __restrict__ Xgl,
    const short* __restrict__ Xah, const short* __restrict__ Xal,
    const float* __restrict__ Wg, const float* __restrict__ Wa,
    float* __restrict__ Yfull) {
  const int which = blockIdx.z;
  const int kc    = blockIdx.y;
  const short* Xh = which ? Xah : Xgh;
  const short* Xl = which ? Xal : Xgl;
  const float* W  = which ? Wa  : Wg;
  float* Y = Yfull + (size_t)which * 540000;
  const int n0 = blockIdx.x * 64;
  const int sb = (kc * 43) >> 3;
  const int se = ((kc + 1) * 43) >> 3;

  __shared__ short Bh[64 * 64], Bl[64 * 64];

  const int tid = threadIdx.x;
  const int lane = tid & 63, wid = tid >> 6;
  const int lr = lane & 15, lg = lane >> 4;

  // this thread's two staging chunks: rows row0/row0+32, k-slot s8
  const int row0 = tid >> 3, s8 = tid & 7;
  const int row1 = row0 + 32;
  const int off0 = (row0 << 6) + ((s8 ^ (row0 & 7)) << 3);
  const int off1 = (row1 << 6) + ((s8 ^ (row1 & 7)) << 3);

  f32x4 acc[4][4] = {};
  float4 pa0, pb0, pa1, pb1;   // prefetch regs

  loadW8(W, n0 + row0, sb * 64 + s8 * 8, pa0, pb0);
  loadW8(W, n0 + row1, sb * 64 + s8 * 8, pa1, pb1);

  for (int t = sb; t < se; ++t) {
    const int k0 = t * 64;
    // convert prefetched W to hi/lo and write LDS
    {
      const float v0[8] = {pa0.x, pa0.y, pa0.z, pa0.w, pb0.x, pb0.y, pb0.z, pb0.w};
      const float v1[8] = {pa1.x, pa1.y, pa1.z, pa1.w, pb1.x, pb1.y, pb1.z, pb1.w};
      short8 h0, l0, h1, l1;
#pragma unroll
      for (int e = 0; e < 8; ++e) {
        short hh, ll;
        split_hl(v0[e], hh, ll); h0[e] = hh; l0[e] = ll;
        split_hl(v1[e], hh, ll); h1[e] = hh; l1[e] = ll;
      }
      *(short8*)&Bh[off0] = h0; *(short8*)&Bl[off0] = l0;
      *(short8*)&Bh[off1] = h1; *(short8*)&Bl[off1] = l1;
    }
    // issue next step's W loads (latency hides under barrier+MFMA)
    if (t + 1 < se) {
      loadW8(W, n0 + row0, (t + 1) * 64 + s8 * 8, pa0, pb0);
      loadW8(W, n0 + row1, (t + 1) * 64 + s8 * 8, pa1, pb1);
    }
    __syncthreads();
#pragma unroll
    for (int ks = 0; ks < 2; ++ks) {
      const int kst = k0 + ks * 32 + lg * 8;
      short8 ah[4], al[4], bh[4], bl[4];
#pragma unroll
      for (int nt = 0; nt < 4; ++nt) {
        const int brow = nt * 16 + lr;
        const int boff = (brow << 6) + (((ks * 4 + lg) ^ (brow & 7)) << 3);
        bh[nt] = *(const short8*)&Bh[boff];
        bl[nt] = *(const short8*)&Bl[boff];
      }
#pragma unroll
      for (int j = 0; j < 4; ++j) {
        const int row = (wid + 4 * j) * 16 + lr;
        ah[j] = zero8();
        al[j] = zero8();
        if (row < 200 && kst < EMBED) {
          const size_t off = (size_t)row * XSTR + kst;
          ah[j] = *(const short8*)&Xh[off];
          al[j] = *(const short8*)&Xl[off];
        }
      }
#pragma unroll
      for (int j = 0; j < 4; ++j)
#pragma unroll
        for (int nt = 0; nt < 4; ++nt) {
          acc[j][nt] = __builtin_amdgcn_mfma_f32_16x16x32_bf16(ah[j], bh[nt], acc[j][nt], 0, 0, 0);
          acc[j][nt] = __builtin_amdgcn_mfma_f32_16x16x32_bf16(ah[j], bl[nt], acc[j][nt], 0, 0, 0);
          acc[j][nt] = __builtin_amdgcn_mfma_f32_16x16x32_bf16(al[j], bh[nt], acc[j][nt], 0, 0, 0);
        }
    }
    __syncthreads();
  }
  // epilogue: atomic accumulate. D col = lane&15, row = (lane>>4)*4 + r
#pragma unroll
  for (int j = 0; j < 4; ++j) {
    const int r0 = (wid + 4 * j) * 16 + lg * 4;
    if (r0 >= 200) continue;
#pragma unroll
    for (int nt = 0; nt < 4; ++nt) {
      const int col = n0 + nt * 16 + lr;
      if (col < EMBED) {
#pragma unroll
        for (int r = 0; r < 4; ++r)
          if (r0 + r < 200)
            unsafeAtomicAdd(&Y[(size_t)(r0 + r) * EMBED + col], acc[j][nt][r]);
      }
    }
  }
}

// ---------------------------------------------------------------------------
// Kernel 4a: sim partials from single Y plane; atomicAdd into sim buffer.
// Block (kc2, b2), SKC=36, grid (75, 2).
// ---------------------------------------------------------------------------
#define SKC 36
__global__ __launch_bounds__(256) void sim_gemm_kernel(
    const float* __restrict__ Yfull, float* __restrict__ sim) {
  const int kc2 = blockIdx.x;  // 0..74
  const int b2  = blockIdx.y;  // 0..1
  __shared__ float Gs[112][SKC];
  __shared__ float As[112][SKC];
  const int tid = threadIdx.x;
  for (int e = tid; e < 100 * 9; e += 256) {
    const int r = e / 9, c = e % 9;
    const size_t base = (size_t)(b2 * 100 + r) * EMBED + kc2 * SKC + c * 4;
    *(float4*)&Gs[r][c * 4] = *(const float4*)&Yfull[base];
    *(float4*)&As[r][c * 4] = *(const float4*)&Yfull[540000 + base];
  }
  __syncthreads();
  const int tx = tid & 15, ty = tid >> 4;
  float acc[7][7] = {};
  for (int kd = 0; kd < SKC; kd += 4) {
    float4 g[7], a[7];
#pragma unroll
    for (int jq = 0; jq < 7; ++jq) g[jq] = *(const float4*)&Gs[tx + 16 * jq][kd];
#pragma unroll
    for (int ik = 0; ik < 7; ++ik) a[ik] = *(const float4*)&As[ty + 16 * ik][kd];
#pragma unroll
    for (int ik = 0; ik < 7; ++ik)
#pragma unroll
      for (int jq = 0; jq < 7; ++jq)
        acc[ik][jq] += a[ik].x * g[jq].x + a[ik].y * g[jq].y +
                       a[ik].z * g[jq].z + a[ik].w * g[jq].w;
  }
  float* pb = sim + (size_t)b2 * 10000;
#pragma unroll
  for (int ik = 0; ik < 7; ++ik) {
    const int k = ty + 16 * ik;
    if (k < 100) {
#pragma unroll
      for (int jq = 0; jq < 7; ++jq) {
        const int q = tx + 16 * jq;
        if (q < 100) unsafeAtomicAdd(&pb[k * 100 + q], acc[ik][jq]);
      }
    }
  }
}

// ---------------------------------------------------------------------------
// Kernel 4b: softmax over q (dim 1) from sim buffer, write out.
// grid 200 (one (b2,k) column), block 128 (threads 0..99 = q).
// ---------------------------------------------------------------------------
__global__ __launch_bounds__(128) void softmax_kernel(
    const float* __restrict__ sim, float* __restrict__ out) {
  const int col = blockIdx.x;          // 0..199
  const int b2 = col / 100, k = col % 100;
  const int tid = threadIdx.x;
  __shared__ float red[2];
  float v = -1e30f;
  if (tid < 100)
    v = sim[(size_t)b2 * 10000 + k * 100 + tid] / sqrtf(384.0f);
  float m = v;
#pragma unroll
  for (int off = 32; off; off >>= 1) m = fmaxf(m, __shfl_down(m, off, 64));
  if ((tid & 63) == 0) red[tid >> 6] = m;
  __syncthreads();
  m = fmaxf(red[0], red[1]);
  const float e = (tid < 100) ? expf(v - m) : 0.f;
  float d = e;
#pragma unroll
  for (int off = 32; off; off >>= 1) d += __shfl_down(d, off, 64);
  __syncthreads();
  if ((tid & 63) == 0) red[tid >> 6] = d;
  __syncthreads();
  d = red[0] + red[1];
  if (tid < 100) out[((size_t)b2 * 100 + tid) * 100 + k] = e / d;
}

// ---------------------------------------------------------------------------
extern "C" void kernel_launch(void* const* d_in, const int* in_sizes, int n_in,
                              void* d_out, int out_size, void* d_ws, size_t ws_size,
                              hipStream_t stream) {
  const float* g_samples = (const float*)d_in[0];
  const float* a_samples = (const float*)d_in[1];
  const float* g_logits  = (const float*)d_in[2];
  const float* a_logits  = (const float*)d_in[3];
  const float* g_boxes   = (const float*)d_in[4];
  const float* a_boxes   = (const float*)d_in[5];
  const float* W_ground  = (const float*)d_in[6];
  const float* W_aerial  = (const float*)d_in[7];
  const float* pos_enc   = (const float*)d_in[8];
  float* out = (float*)d_out;
  float* ws  = (float*)d_ws;

  // ws layout (floats):
  float* boxes_px = ws;                          // 1600 (reserve 2048)
  short* Xgh = (short*)(ws + 2048);              // each X array: 270,400 floats
  short* Xgl = (short*)(ws + 2048 + 270400);
  short* Xah = (short*)(ws + 2048 + 540800);
  short* Xal = (short*)(ws + 2048 + 811200);
  float* Yfull = ws + 1083648;                   // 1,080,000 f (2 x 200 x 2700)
  float* simb  = ws + 2163648;                   // 20,000 f  (2 x 100 x 100)

  topk_boxes_kernel<<<4, 256, 0, stream>>>(g_logits, a_logits, g_boxes, a_boxes, boxes_px);
  roi_kernel<<<2400, 256, 0, stream>>>(g_samples, a_samples, boxes_px, pos_enc,
                                       Xgh, Xgl, Xah, Xal);
  zero_kernel<<<1075, 256, 0, stream>>>((float4*)Yfull, 275000);  // Y + sim contiguous
  gemm_kernel<<<dim3(43, NKC, 2), 256, 0, stream>>>(Xgh, Xgl, Xah, Xal,
                                                    W_ground, W_aerial, Yfull);
  sim_gemm_kernel<<<dim3(NSIMKC, 2), 256, 0, stream>>>(Yfull, simb);
  softmax_kernel<<<200, 128, 0, stream>>>(simb, out);
}